// Round 15
// baseline (384.133 us; speedup 1.0000x reference)
//
#include <hip/hip_runtime.h>

#define NDIM 128
#define EDIM 64
#define BN_EPS 1e-5f
#define SPAN 64          // slots per wave (edge pass)
#define WPB  4           // waves per block (edge pass)
#define LPAD (NDIM + 4)  // edge-pass msg row pitch (f32)
#define PITCH 136        // node-mlp activation LDS pitch (shorts)
#define WPITCH 136       // node-mlp weight LDS pitch (shorts)

typedef __attribute__((ext_vector_type(8))) short short8v;
typedef __attribute__((ext_vector_type(4))) float float4v;

static __device__ __forceinline__ unsigned short f2bf(float f) {
    union { float f; unsigned u; } c; c.f = f;
    const unsigned r = (c.u + 0x7fffu + ((c.u >> 16) & 1u)) >> 16;
    return (unsigned short)r;
}

static __device__ __forceinline__ short8v pack_bf(const float4 f0, const float4 f1) {
    short8v a;
    a[0] = (short)f2bf(f0.x); a[1] = (short)f2bf(f0.y);
    a[2] = (short)f2bf(f0.z); a[3] = (short)f2bf(f0.w);
    a[4] = (short)f2bf(f1.x); a[5] = (short)f2bf(f1.y);
    a[6] = (short)f2bf(f1.z); a[7] = (short)f2bf(f1.w);
    return a;
}

static __device__ __forceinline__ short8v cvt_row(const float* __restrict__ arow, int k0) {
    const float4 f0 = *reinterpret_cast<const float4*>(arow + k0);
    const float4 f1 = *reinterpret_cast<const float4*>(arow + k0 + 4);
    return pack_bf(f0, f1);
}

// ---------------------------------------------------------------------------
// CSR build step 1 + ea conversion (fused). Cvt loop manually unrolled 4x
// with STRIDED batching: 8 independent coalesced loads in flight per wave
// before any dependent pack/store (kills the per-iteration HBM round-trip).
// ---------------------------------------------------------------------------
__global__ __launch_bounds__(256) void hist_cvt_k(
    const int* __restrict__ ei, int* __restrict__ deg,
    const float* __restrict__ ea, unsigned short* __restrict__ eab,
    int E, int doCvt)
{
    const long tid0 = (long)blockIdx.x * blockDim.x + threadIdx.x;
    const long step = (long)gridDim.x * blockDim.x;
    for (long e = tid0; e < E; e += step)
        atomicAdd(&deg[ei[E + e]], 1);
    if (doCvt) {
        const long n8 = (long)E * (EDIM / 8);
        long p = tid0;
        for (; p + 3 * step < n8; p += 4 * step) {
            const long p0 = p, p1 = p + step, p2 = p + 2 * step, p3 = p + 3 * step;
            const float4 a0 = *reinterpret_cast<const float4*>(ea + p0 * 8);
            const float4 b0 = *reinterpret_cast<const float4*>(ea + p0 * 8 + 4);
            const float4 a1 = *reinterpret_cast<const float4*>(ea + p1 * 8);
            const float4 b1 = *reinterpret_cast<const float4*>(ea + p1 * 8 + 4);
            const float4 a2 = *reinterpret_cast<const float4*>(ea + p2 * 8);
            const float4 b2 = *reinterpret_cast<const float4*>(ea + p2 * 8 + 4);
            const float4 a3 = *reinterpret_cast<const float4*>(ea + p3 * 8);
            const float4 b3 = *reinterpret_cast<const float4*>(ea + p3 * 8 + 4);
            *reinterpret_cast<short8v*>(eab + p0 * 8) = pack_bf(a0, b0);
            *reinterpret_cast<short8v*>(eab + p1 * 8) = pack_bf(a1, b1);
            *reinterpret_cast<short8v*>(eab + p2 * 8) = pack_bf(a2, b2);
            *reinterpret_cast<short8v*>(eab + p3 * 8) = pack_bf(a3, b3);
        }
        for (; p < n8; p += step) {
            const float4 a = *reinterpret_cast<const float4*>(ea + p * 8);
            const float4 b = *reinterpret_cast<const float4*>(ea + p * 8 + 4);
            *reinterpret_cast<short8v*>(eab + p * 8) = pack_bf(a, b);
        }
    }
}

// ---------------------------------------------------------------------------
// CSR build step 2: exclusive scan of deg -> rowptr + cursor (8 elems/thread).
// ---------------------------------------------------------------------------
__global__ __launch_bounds__(1024) void scan_build(
    int* __restrict__ cursor, int* __restrict__ rowptr, int N)
{
    __shared__ int wsums[16];
    __shared__ int run_s;
    const int tid  = threadIdx.x;
    const int lane = tid & 63;
    const int w    = tid >> 6;
    if (tid == 0) run_s = 0;
    __syncthreads();
    for (int base = 0; base < N; base += 8192) {
        const int i0 = base + tid * 8;
        int v[8];
#pragma unroll
        for (int k = 0; k < 8; ++k) v[k] = 0;
        if (i0 + 7 < N) {
            const int4 a = *reinterpret_cast<const int4*>(cursor + i0);
            const int4 b = *reinterpret_cast<const int4*>(cursor + i0 + 4);
            v[0] = a.x; v[1] = a.y; v[2] = a.z; v[3] = a.w;
            v[4] = b.x; v[5] = b.y; v[6] = b.z; v[7] = b.w;
        } else if (i0 < N) {
            for (int k = 0; k < 8 && i0 + k < N; ++k) v[k] = cursor[i0 + k];
        }
        const int tsum = ((v[0] + v[1]) + (v[2] + v[3])) + ((v[4] + v[5]) + (v[6] + v[7]));
        int incl = tsum;
#pragma unroll
        for (int off = 1; off < 64; off <<= 1) {
            int t = __shfl_up(incl, off, 64);
            if (lane >= off) incl += t;
        }
        if (lane == 63) wsums[w] = incl;
        __syncthreads();
        if (w == 0) {
            int s = (lane < 16) ? wsums[lane] : 0;
#pragma unroll
            for (int off = 1; off < 16; off <<= 1) {
                int t = __shfl_up(s, off, 64);
                if (lane >= off) s += t;
            }
            if (lane < 16) wsums[lane] = s;
        }
        __syncthreads();
        const int waveoff = (w > 0) ? wsums[w - 1] : 0;
        int acc = run_s + waveoff + incl - tsum;
        if (i0 + 7 < N) {
            int4 ra, rb;
            ra.x = acc;            ra.y = acc + v[0];
            ra.z = ra.y + v[1];    ra.w = ra.z + v[2];
            rb.x = ra.w + v[3];    rb.y = rb.x + v[4];
            rb.z = rb.y + v[5];    rb.w = rb.z + v[6];
            *reinterpret_cast<int4*>(rowptr + i0) = ra;
            *reinterpret_cast<int4*>(rowptr + i0 + 4) = rb;
            *reinterpret_cast<int4*>(cursor + i0) = ra;
            *reinterpret_cast<int4*>(cursor + i0 + 4) = rb;
        } else if (i0 < N) {
            for (int k = 0; k < 8 && i0 + k < N; ++k) {
                rowptr[i0 + k] = acc; cursor[i0 + k] = acc; acc += v[k];
            }
        }
        __syncthreads();
        if (tid == 0) run_s += wsums[15];
        __syncthreads();
    }
    if (tid == 0) rowptr[N] = run_s;
}

// ---------------------------------------------------------------------------
// CSR build step 3: scatter src/dst into slot order + inverse map eidp.
// ---------------------------------------------------------------------------
__global__ __launch_bounds__(256) void scatter_k(
    const int* __restrict__ ei, int* __restrict__ cursor,
    int* __restrict__ srcp, int* __restrict__ dstp,
    int* __restrict__ eidp, int E)
{
    const int e = blockIdx.x * blockDim.x + threadIdx.x;
    if (e < E) {
        const int d = ei[E + e];
        const int p = atomicAdd(&cursor[d], 1);
        srcp[p] = ei[e];
        dstp[p] = d;
        eidp[p] = e;
    }
}

// ---------------------------------------------------------------------------
// Weight prep (merged): We1/We2 -> [128][64] bf16T; W1..W4 -> [128][128] bf16T.
// ---------------------------------------------------------------------------
__global__ __launch_bounds__(128) void prep_all(
    const float* __restrict__ We1, const float* __restrict__ We2,
    const float* __restrict__ W1, const float* __restrict__ W2,
    const float* __restrict__ W3, const float* __restrict__ W4,
    unsigned short* __restrict__ WeT1, unsigned short* __restrict__ WeT2,
    unsigned short* __restrict__ W1T, unsigned short* __restrict__ W2T,
    unsigned short* __restrict__ W3T, unsigned short* __restrict__ W4T)
{
    const int c = blockIdx.x;    // 0..127 output column
    const int k = threadIdx.x;   // 0..127
    if (k < EDIM) {
        WeT1[c * EDIM + k] = f2bf(We1[k * NDIM + c]);
        WeT2[c * EDIM + k] = f2bf(We2[k * NDIM + c]);
    }
    W1T[c * NDIM + k] = f2bf(W1[k * NDIM + c]);
    W2T[c * NDIM + k] = f2bf(W2[k * NDIM + c]);
    W3T[c * NDIM + k] = f2bf(W3[k * NDIM + c]);
    W4T[c * NDIM + k] = f2bf(W4[k * NDIM + c]);
}

// ---------------------------------------------------------------------------
// Edge pass: MFMA + software-pipelined segmented accumulate (r12 form).
// ---------------------------------------------------------------------------
template <bool PERM>
__global__ __launch_bounds__(256) void edge_mfma(
    const float* __restrict__ xnode,
    const float* __restrict__ ea,
    const unsigned short* __restrict__ eab,
    const int*   __restrict__ srcp,
    const int*   __restrict__ eidp,
    const int*   __restrict__ dstp,
    const unsigned short* __restrict__ WeT,
    const float* __restrict__ be,
    float*       __restrict__ aggr,
    int E)
{
    __shared__ float msg[WPB][16][LPAD];

    const int tid   = threadIdx.x;
    const int lane  = tid & 63;
    const int wv    = tid >> 6;
    const int span0 = (blockIdx.x * WPB + wv) * SPAN;
    if (span0 >= E) return;

    const int m16 = lane & 15;
    const int kg  = lane >> 4;
    const int k0a = kg * 8;

    short8v bfrag[2][8];
#pragma unroll
    for (int kk = 0; kk < 2; ++kk)
#pragma unroll
        for (int nt = 0; nt < 8; ++nt) {
            const int col = nt * 16 + m16;
            bfrag[kk][nt] = *reinterpret_cast<const short8v*>(&WeT[col * EDIM + kk * 32 + k0a]);
        }

    const int c0 = lane, c1 = lane + 64;
    const float be0 = be[c0], be1 = be[c1];
    float* msgw = &msg[wv][0][0];

    float a0 = 0.f, a1 = 0.f;

    if (span0 + SPAN <= E) {
        int   sr_c[16], ds_c[16];
        float xv0_c[16], xv1_c[16];
        short8v af_n[2];
        short8v af_nn[2];
        float4 eaf_n[4];
        float4 eaf_nn[4];

        int eid1 = 0, eid2 = 0, eid3 = 0;
        if (PERM) {
            eid1 = eidp[span0 + 16 + m16];
            eid2 = eidp[span0 + 32 + m16];
            eid3 = eidp[span0 + 48 + m16];
        }

#pragma unroll
        for (int s = 0; s < 16; ++s) { sr_c[s] = srcp[span0 + s]; ds_c[s] = dstp[span0 + s]; }
#pragma unroll
        for (int s = 0; s < 16; ++s) {
            xv0_c[s] = xnode[(long)sr_c[s] * NDIM + c0];
            xv1_c[s] = xnode[(long)sr_c[s] * NDIM + c1];
        }
        {
            short8v af0, af1;
            if (PERM) {
                const unsigned short* arow = eab + (size_t)eidp[span0 + m16] * EDIM;
                af0 = *reinterpret_cast<const short8v*>(arow + k0a);
                af1 = *reinterpret_cast<const short8v*>(arow + 32 + k0a);
            } else {
                const float* arow = ea + (long)eidp[span0 + m16] * EDIM;
                af0 = cvt_row(arow, k0a);
                af1 = cvt_row(arow, 32 + k0a);
            }
#pragma unroll
            for (int nt = 0; nt < 8; ++nt) {
                float4v acc = (float4v){0.f, 0.f, 0.f, 0.f};
                acc = __builtin_amdgcn_mfma_f32_16x16x32_bf16(af0, bfrag[0][nt], acc, 0, 0, 0);
                acc = __builtin_amdgcn_mfma_f32_16x16x32_bf16(af1, bfrag[1][nt], acc, 0, 0, 0);
#pragma unroll
                for (int r = 0; r < 4; ++r)
                    msgw[(kg * 4 + r) * LPAD + nt * 16 + m16] = acc[r];
            }
        }
        if (PERM) {
            const unsigned short* arow = eab + (size_t)eid1 * EDIM;
            af_n[0] = *reinterpret_cast<const short8v*>(arow + k0a);
            af_n[1] = *reinterpret_cast<const short8v*>(arow + 32 + k0a);
        } else {
            const float* arow = ea + (long)eidp[span0 + 16 + m16] * EDIM;
            eaf_n[0] = *reinterpret_cast<const float4*>(arow + k0a);
            eaf_n[1] = *reinterpret_cast<const float4*>(arow + k0a + 4);
            eaf_n[2] = *reinterpret_cast<const float4*>(arow + 32 + k0a);
            eaf_n[3] = *reinterpret_cast<const float4*>(arow + 32 + k0a + 4);
        }

        int dcur = ds_c[0];

#pragma unroll
        for (int t = 0; t < SPAN / 16; ++t) {
            const int base = span0 + t * 16;
            const bool hn  = (t + 1 < SPAN / 16);
            const bool hnn = (t + 2 < SPAN / 16);
            int   sr_n[16], ds_n[16];
            float xv0_n[16], xv1_n[16];

            if (hn) {
#pragma unroll
                for (int s = 0; s < 16; ++s) {
                    sr_n[s] = srcp[base + 16 + s];
                    ds_n[s] = dstp[base + 16 + s];
                }
#pragma unroll
                for (int s = 0; s < 16; ++s) {
                    xv0_n[s] = xnode[(long)sr_n[s] * NDIM + c0];
                    xv1_n[s] = xnode[(long)sr_n[s] * NDIM + c1];
                }
            }

            if (hnn) {
                if (PERM) {
                    const int eidx = (t == 0) ? eid2 : eid3;
                    const unsigned short* arow = eab + (size_t)eidx * EDIM;
                    af_nn[0] = *reinterpret_cast<const short8v*>(arow + k0a);
                    af_nn[1] = *reinterpret_cast<const short8v*>(arow + 32 + k0a);
                } else {
                    const float* arow = ea + (long)eidp[base + 32 + m16] * EDIM;
                    eaf_nn[0] = *reinterpret_cast<const float4*>(arow + k0a);
                    eaf_nn[1] = *reinterpret_cast<const float4*>(arow + k0a + 4);
                    eaf_nn[2] = *reinterpret_cast<const float4*>(arow + 32 + k0a);
                    eaf_nn[3] = *reinterpret_cast<const float4*>(arow + 32 + k0a + 4);
                }
            }

#pragma unroll
            for (int s = 0; s < 16; ++s) {
                if (ds_c[s] != dcur) {
                    atomicAdd(&aggr[(long)dcur * NDIM + c0], a0);
                    atomicAdd(&aggr[(long)dcur * NDIM + c1], a1);
                    a0 = 0.f; a1 = 0.f; dcur = ds_c[s];
                }
                a0 += fmaxf(xv0_c[s] + msgw[s * LPAD + c0] + be0, 0.f);
                a1 += fmaxf(xv1_c[s] + msgw[s * LPAD + c1] + be1, 0.f);
            }

            if (hn) {
                short8v af0, af1;
                if (PERM) { af0 = af_n[0]; af1 = af_n[1]; }
                else      { af0 = pack_bf(eaf_n[0], eaf_n[1]); af1 = pack_bf(eaf_n[2], eaf_n[3]); }
#pragma unroll
                for (int nt = 0; nt < 8; ++nt) {
                    float4v acc = (float4v){0.f, 0.f, 0.f, 0.f};
                    acc = __builtin_amdgcn_mfma_f32_16x16x32_bf16(af0, bfrag[0][nt], acc, 0, 0, 0);
                    acc = __builtin_amdgcn_mfma_f32_16x16x32_bf16(af1, bfrag[1][nt], acc, 0, 0, 0);
#pragma unroll
                    for (int r = 0; r < 4; ++r)
                        msgw[(kg * 4 + r) * LPAD + nt * 16 + m16] = acc[r];
                }
                if (PERM) {
                    af_n[0] = af_nn[0]; af_n[1] = af_nn[1];
                } else {
#pragma unroll
                    for (int i = 0; i < 4; ++i) eaf_n[i] = eaf_nn[i];
                }
#pragma unroll
                for (int s = 0; s < 16; ++s) {
                    sr_c[s] = sr_n[s]; ds_c[s] = ds_n[s];
                    xv0_c[s] = xv0_n[s]; xv1_c[s] = xv1_n[s];
                }
            }
        }
        atomicAdd(&aggr[(long)dcur * NDIM + c0], a0);
        atomicAdd(&aggr[(long)dcur * NDIM + c1], a1);
    } else {
        const int spanEnd = E;
        int dcur = dstp[span0];
        for (int t = 0; t < SPAN / 16; ++t) {
            const int base = span0 + t * 16;
            if (base >= spanEnd) break;

            const int slot = (base + m16 < E) ? base + m16 : E - 1;
            short8v afrag[2];
            if (PERM) {
                const unsigned short* arow = eab + (size_t)eidp[slot] * EDIM;
                afrag[0] = *reinterpret_cast<const short8v*>(arow + k0a);
                afrag[1] = *reinterpret_cast<const short8v*>(arow + 32 + k0a);
            } else {
                const float* arow = ea + (long)eidp[slot] * EDIM;
                afrag[0] = cvt_row(arow, k0a);
                afrag[1] = cvt_row(arow, 32 + k0a);
            }

#pragma unroll
            for (int nt = 0; nt < 8; ++nt) {
                float4v acc = (float4v){0.f, 0.f, 0.f, 0.f};
                acc = __builtin_amdgcn_mfma_f32_16x16x32_bf16(afrag[0], bfrag[0][nt], acc, 0, 0, 0);
                acc = __builtin_amdgcn_mfma_f32_16x16x32_bf16(afrag[1], bfrag[1][nt], acc, 0, 0, 0);
#pragma unroll
                for (int r = 0; r < 4; ++r)
                    msgw[(kg * 4 + r) * LPAD + nt * 16 + m16] = acc[r];
            }

            for (int s = 0; s < 16; ++s) {
                const int gs = base + s;
                if (gs >= spanEnd) break;
                const int d  = dstp[gs];
                const int sr = srcp[gs];
                if (d != dcur) {
                    atomicAdd(&aggr[(long)dcur * NDIM + c0], a0);
                    atomicAdd(&aggr[(long)dcur * NDIM + c1], a1);
                    a0 = 0.f; a1 = 0.f; dcur = d;
                }
                const float xv0 = xnode[(long)sr * NDIM + c0];
                const float xv1 = xnode[(long)sr * NDIM + c1];
                a0 += fmaxf(xv0 + msgw[s * LPAD + c0] + be0, 0.f);
                a1 += fmaxf(xv1 + msgw[s * LPAD + c1] + be1, 0.f);
            }
        }
        atomicAdd(&aggr[(long)dcur * NDIM + c0], a0);
        atomicAdd(&aggr[(long)dcur * NDIM + c1], a1);
    }
}

// ---------------------------------------------------------------------------
// Node MLP via MFMA, weights staged in LDS (r14 form, kept).
// ---------------------------------------------------------------------------
template <bool FINAL_RELU, bool STATS>
__global__ __launch_bounds__(256) void node_mlp_mfma(
    const float* xin,                    // may alias out (same-row read->write)
    const float* __restrict__ aggr,
    const unsigned short* __restrict__ W1T, const float* __restrict__ b1,
    const unsigned short* __restrict__ W2T, const float* __restrict__ b2,
    float* out,
    float* __restrict__ stats,
    int N)
{
    __shared__ unsigned short w1s[NDIM][WPITCH];
    __shared__ unsigned short w2s[NDIM][WPITCH];
    __shared__ unsigned short in_lds[16][PITCH];
    __shared__ unsigned short t_lds[16][PITCH];

    const int tid  = threadIdx.x;
    const int lane = tid & 63;
    const int wv   = tid >> 6;
    const int wn0  = wv * 32;
    const int m16  = lane & 15;
    const int rg   = lane >> 4;

    {
        const int col = tid >> 1;
        const int h   = (tid & 1) * 64;
#pragma unroll
        for (int j = 0; j < 8; ++j) {
            *reinterpret_cast<short8v*>(&w1s[col][h + j * 8]) =
                *reinterpret_cast<const short8v*>(&W1T[col * NDIM + h + j * 8]);
            *reinterpret_cast<short8v*>(&w2s[col][h + j * 8]) =
                *reinterpret_cast<const short8v*>(&W2T[col * NDIM + h + j * 8]);
        }
    }
    float bias1[2], bias2[2];
#pragma unroll
    for (int nt = 0; nt < 2; ++nt) {
        bias1[nt] = b1[wn0 + nt * 16 + m16];
        bias2[nt] = b2[wn0 + nt * 16 + m16];
    }
    __syncthreads();

    float ss[2] = {0.f, 0.f}, sq[2] = {0.f, 0.f};

    const int ntile = (N + 15) >> 4;
    for (int tile = blockIdx.x; tile < ntile; tile += gridDim.x) {
        const int nb = tile << 4;

        {
            const int row = tid >> 4;
            const int ch  = tid & 15;
            const int gr  = nb + row;
            short8v pk = (short8v){0, 0, 0, 0, 0, 0, 0, 0};
            if (gr < N) {
                const float4* xp = reinterpret_cast<const float4*>(xin  + (size_t)gr * NDIM + ch * 8);
                const float4* ap = reinterpret_cast<const float4*>(aggr + (size_t)gr * NDIM + ch * 8);
                const float4 x0 = xp[0], x1 = xp[1];
                const float4 g0 = ap[0], g1 = ap[1];
                pk[0] = (short)f2bf(x0.x + g0.x); pk[1] = (short)f2bf(x0.y + g0.y);
                pk[2] = (short)f2bf(x0.z + g0.z); pk[3] = (short)f2bf(x0.w + g0.w);
                pk[4] = (short)f2bf(x1.x + g1.x); pk[5] = (short)f2bf(x1.y + g1.y);
                pk[6] = (short)f2bf(x1.z + g1.z); pk[7] = (short)f2bf(x1.w + g1.w);
            }
            *reinterpret_cast<short8v*>(&in_lds[row][ch * 8]) = pk;
        }
        __syncthreads();

        short8v af[4];
#pragma unroll
        for (int kt = 0; kt < 4; ++kt)
            af[kt] = *reinterpret_cast<const short8v*>(&in_lds[m16][kt * 32 + rg * 8]);
        float4v acc[2];
#pragma unroll
        for (int nt = 0; nt < 2; ++nt) {
            acc[nt] = (float4v){0.f, 0.f, 0.f, 0.f};
#pragma unroll
            for (int kt = 0; kt < 4; ++kt) {
                const short8v bf = *reinterpret_cast<const short8v*>(
                    &w1s[wn0 + nt * 16 + m16][kt * 32 + rg * 8]);
                acc[nt] = __builtin_amdgcn_mfma_f32_16x16x32_bf16(af[kt], bf, acc[nt], 0, 0, 0);
            }
        }
#pragma unroll
        for (int nt = 0; nt < 2; ++nt)
#pragma unroll
            for (int r = 0; r < 4; ++r) {
                const float v = fmaxf(acc[nt][r] + bias1[nt], 0.f);
                t_lds[rg * 4 + r][wn0 + nt * 16 + m16] = f2bf(v);
            }
        __syncthreads();

#pragma unroll
        for (int kt = 0; kt < 4; ++kt)
            af[kt] = *reinterpret_cast<const short8v*>(&t_lds[m16][kt * 32 + rg * 8]);
        float4v acc2[2];
#pragma unroll
        for (int nt = 0; nt < 2; ++nt) {
            acc2[nt] = (float4v){0.f, 0.f, 0.f, 0.f};
#pragma unroll
            for (int kt = 0; kt < 4; ++kt) {
                const short8v bf = *reinterpret_cast<const short8v*>(
                    &w2s[wn0 + nt * 16 + m16][kt * 32 + rg * 8]);
                acc2[nt] = __builtin_amdgcn_mfma_f32_16x16x32_bf16(af[kt], bf, acc2[nt], 0, 0, 0);
            }
        }

#pragma unroll
        for (int nt = 0; nt < 2; ++nt)
#pragma unroll
            for (int r = 0; r < 4; ++r) {
                const int node = nb + rg * 4 + r;
                if (node < N) {
                    float o = acc2[nt][r] + bias2[nt];
                    if (FINAL_RELU) o = fmaxf(o, 0.f);
                    out[(size_t)node * NDIM + wn0 + nt * 16 + m16] = o;
                    if (STATS) { ss[nt] += o; sq[nt] += o * o; }
                }
            }
    }

    if (STATS) {
#pragma unroll
        for (int nt = 0; nt < 2; ++nt) {
            float s = ss[nt], q = sq[nt];
            s += __shfl_xor(s, 16); q += __shfl_xor(q, 16);
            s += __shfl_xor(s, 32); q += __shfl_xor(q, 32);
            if (rg == 0) {
                atomicAdd(&stats[wn0 + nt * 16 + m16], s);
                atomicAdd(&stats[NDIM + wn0 + nt * 16 + m16], q);
            }
        }
    }
}

// ---------------------------------------------------------------------------
// BatchNorm apply (in place), 4x strided unroll for load pipelining.
// ---------------------------------------------------------------------------
__global__ __launch_bounds__(256) void bn_apply(
    float* out,
    const float* __restrict__ stats,
    const float* __restrict__ gamma,
    const float* __restrict__ beta,
    int N)
{
    __shared__ float sc_s[NDIM];
    __shared__ float sh_s[NDIM];
    const float invN = 1.f / (float)N;
    if (threadIdx.x < NDIM) {
        const int f = threadIdx.x;
        const float mean = stats[f] * invN;
        const float var  = stats[NDIM + f] * invN - mean * mean;
        const float sc   = gamma[f] * rsqrtf(var + BN_EPS);
        sc_s[f] = sc;
        sh_s[f] = beta[f] - mean * sc;
    }
    __syncthreads();

    const int total4 = N * (NDIM / 4);
    const int step   = gridDim.x * blockDim.x;
    float4* o4 = reinterpret_cast<float4*>(out);
    int idx = blockIdx.x * blockDim.x + threadIdx.x;
    for (; idx + 3 * step < total4; idx += 4 * step) {
        const int i0 = idx, i1 = idx + step, i2 = idx + 2 * step, i3 = idx + 3 * step;
        float4 p0 = o4[i0], p1 = o4[i1], p2 = o4[i2], p3 = o4[i3];
        const int f0 = (i0 & 31) * 4, f1 = (i1 & 31) * 4, f2 = (i2 & 31) * 4, f3 = (i3 & 31) * 4;
        p0.x = p0.x * sc_s[f0 + 0] + sh_s[f0 + 0]; p0.y = p0.y * sc_s[f0 + 1] + sh_s[f0 + 1];
        p0.z = p0.z * sc_s[f0 + 2] + sh_s[f0 + 2]; p0.w = p0.w * sc_s[f0 + 3] + sh_s[f0 + 3];
        p1.x = p1.x * sc_s[f1 + 0] + sh_s[f1 + 0]; p1.y = p1.y * sc_s[f1 + 1] + sh_s[f1 + 1];
        p1.z = p1.z * sc_s[f1 + 2] + sh_s[f1 + 2]; p1.w = p1.w * sc_s[f1 + 3] + sh_s[f1 + 3];
        p2.x = p2.x * sc_s[f2 + 0] + sh_s[f2 + 0]; p2.y = p2.y * sc_s[f2 + 1] + sh_s[f2 + 1];
        p2.z = p2.z * sc_s[f2 + 2] + sh_s[f2 + 2]; p2.w = p2.w * sc_s[f2 + 3] + sh_s[f2 + 3];
        p3.x = p3.x * sc_s[f3 + 0] + sh_s[f3 + 0]; p3.y = p3.y * sc_s[f3 + 1] + sh_s[f3 + 1];
        p3.z = p3.z * sc_s[f3 + 2] + sh_s[f3 + 2]; p3.w = p3.w * sc_s[f3 + 3] + sh_s[f3 + 3];
        o4[i0] = p0; o4[i1] = p1; o4[i2] = p2; o4[i3] = p3;
    }
    for (; idx < total4; idx += step) {
        const int fb = (idx & 31) * 4;
        float4 p = o4[idx];
        p.x = p.x * sc_s[fb + 0] + sh_s[fb + 0];
        p.y = p.y * sc_s[fb + 1] + sh_s[fb + 1];
        p.z = p.z * sc_s[fb + 2] + sh_s[fb + 2];
        p.w = p.w * sc_s[fb + 3] + sh_s[fb + 3];
        o4[idx] = p;
    }
}

// ---------------------------------------------------------------------------
extern "C" void kernel_launch(void* const* d_in, const int* in_sizes, int n_in,
                              void* d_out, int out_size, void* d_ws, size_t ws_size,
                              hipStream_t stream)
{
    const float* x    = (const float*)d_in[0];
    const int*   ei   = (const int*)  d_in[1];
    const float* ea   = (const float*)d_in[2];
    const float* We1  = (const float*)d_in[3];
    const float* be1  = (const float*)d_in[4];
    const float* W1   = (const float*)d_in[5];
    const float* b1   = (const float*)d_in[6];
    const float* W2   = (const float*)d_in[7];
    const float* b2   = (const float*)d_in[8];
    const float* We2  = (const float*)d_in[9];
    const float* be2  = (const float*)d_in[10];
    const float* W3   = (const float*)d_in[11];
    const float* b3   = (const float*)d_in[12];
    const float* W4   = (const float*)d_in[13];
    const float* b4   = (const float*)d_in[14];
    const float* gamma = (const float*)d_in[15];
    const float* beta  = (const float*)d_in[16];

    const int N = in_sizes[0] / NDIM;
    const int E = in_sizes[1] / 2;

    // workspace layout (aggr first; all 16B-aligned)
    float*          aggr   = (float*)d_ws;                            // [N*128]
    unsigned short* WeT1   = (unsigned short*)(aggr + (size_t)N * NDIM);
    unsigned short* WeT2   = WeT1 + NDIM * EDIM;
    unsigned short* W1T    = WeT2 + NDIM * EDIM;                      // [128*128]
    unsigned short* W2T    = W1T + NDIM * NDIM;
    unsigned short* W3T    = W2T + NDIM * NDIM;
    unsigned short* W4T    = W3T + NDIM * NDIM;
    int*            rowptr = (int*)(W4T + NDIM * NDIM);               // [N+1]
    int*            cursor = rowptr + (N + 1);                        // [N]
    int*            srcp   = cursor + N;                              // [E]
    int*            dstp   = srcp + E;                                // [E]
    int*            eidp   = dstp + E;                                // [E]
    float*          stats  = (float*)(eidp + E);                      // [256]
    unsigned short* eab    = (unsigned short*)(stats + 2 * NDIM);     // [E*64] bf16

    const size_t need_perm = (size_t)((char*)eab - (char*)d_ws) + (size_t)E * EDIM * 2 + 64;
    const bool   perm      = ws_size >= need_perm;

    hipMemsetAsync(cursor, 0, (size_t)N * sizeof(int), stream);
    hipMemsetAsync(stats, 0, 2 * NDIM * sizeof(float), stream);

    // ---- CSR build (+ fused ea bf16 conversion) + weight prep ----
    hist_cvt_k<<<2048, 256, 0, stream>>>(ei, cursor, ea, eab, E, perm ? 1 : 0);
    scan_build<<<1, 1024, 0, stream>>>(cursor, rowptr, N);
    scatter_k<<<(E + 255) / 256, 256, 0, stream>>>(ei, cursor, srcp, dstp, eidp, E);
    prep_all<<<NDIM, NDIM, 0, stream>>>(We1, We2, W1, W2, W3, W4,
                                        WeT1, WeT2, W1T, W2T, W3T, W4T);

    const int egrid = (E + WPB * SPAN - 1) / (WPB * SPAN);
    const int mgrid = 512;   // 2 blocks/CU (78KB LDS), ~6 tiles each
    float* h = (float*)d_out;

    // ---- conv1 ----
    hipMemsetAsync(aggr, 0, (size_t)N * NDIM * sizeof(float), stream);
    if (perm)
        edge_mfma<true><<<egrid, 256, 0, stream>>>(x, ea, eab, srcp, eidp, dstp, WeT1, be1, aggr, E);
    else
        edge_mfma<false><<<egrid, 256, 0, stream>>>(x, ea, eab, srcp, eidp, dstp, WeT1, be1, aggr, E);
    node_mlp_mfma<true, false><<<mgrid, 256, 0, stream>>>(x, aggr, W1T, b1, W2T, b2,
                                                          h, nullptr, N);
    // ---- conv2 ----
    hipMemsetAsync(aggr, 0, (size_t)N * NDIM * sizeof(float), stream);
    if (perm)
        edge_mfma<true><<<egrid, 256, 0, stream>>>(h, ea, eab, srcp, eidp, dstp, WeT2, be2, aggr, E);
    else
        edge_mfma<false><<<egrid, 256, 0, stream>>>(h, ea, eab, srcp, eidp, dstp, WeT2, be2, aggr, E);
    node_mlp_mfma<false, true><<<mgrid, 256, 0, stream>>>(h, aggr, W3T, b3, W4T, b4,
                                                          h, stats, N);
    // ---- batch norm ----
    bn_apply<<<1024, 256, 0, stream>>>(h, stats, gamma, beta, N);
}

// Round 16
// 375.438 us; speedup vs baseline: 1.0232x; 1.0232x over previous
//
#include <hip/hip_runtime.h>

#define NDIM 128
#define EDIM 64
#define BN_EPS 1e-5f
#define SPAN 64          // slots per wave (edge pass)
#define WPB  4           // waves per block (edge pass)
#define LPAD (NDIM + 4)  // edge-pass msg row pitch (f32)
#define PITCH 136        // node-mlp activation LDS pitch (shorts)
#define WPITCH 136       // node-mlp weight LDS pitch (shorts)
#define HISTB 256        // hist blocks inside hist_cvt_k

typedef __attribute__((ext_vector_type(8))) short short8v;
typedef __attribute__((ext_vector_type(4))) float float4v;

static __device__ __forceinline__ unsigned short f2bf(float f) {
    union { float f; unsigned u; } c; c.f = f;
    const unsigned r = (c.u + 0x7fffu + ((c.u >> 16) & 1u)) >> 16;
    return (unsigned short)r;
}

static __device__ __forceinline__ short8v pack_bf(const float4 f0, const float4 f1) {
    short8v a;
    a[0] = (short)f2bf(f0.x); a[1] = (short)f2bf(f0.y);
    a[2] = (short)f2bf(f0.z); a[3] = (short)f2bf(f0.w);
    a[4] = (short)f2bf(f1.x); a[5] = (short)f2bf(f1.y);
    a[6] = (short)f2bf(f1.z); a[7] = (short)f2bf(f1.w);
    return a;
}

static __device__ __forceinline__ short8v cvt_row(const float* __restrict__ arow, int k0) {
    const float4 f0 = *reinterpret_cast<const float4*>(arow + k0);
    const float4 f1 = *reinterpret_cast<const float4*>(arow + k0 + 4);
    return pack_bf(f0, f1);
}

// ---------------------------------------------------------------------------
// CSR hist + ea conversion, split BY BLOCK (not by phase): blocks [0,HISTB)
// do only the atomic histogram; the rest do only the pure cvt stream, so no
// streaming wave ever has an atomic in its (in-order) vmcnt queue.
// ---------------------------------------------------------------------------
__global__ __launch_bounds__(256) void hist_cvt_k(
    const int* __restrict__ ei, int* __restrict__ deg,
    const float* __restrict__ ea, unsigned short* __restrict__ eab,
    int E, int doCvt)
{
    if (blockIdx.x < HISTB || !doCvt) {
        const int nb   = doCvt ? HISTB : gridDim.x;
        if (blockIdx.x >= nb) return;
        const long tid0 = (long)blockIdx.x * blockDim.x + threadIdx.x;
        const long step = (long)nb * blockDim.x;
        for (long e = tid0; e < E; e += step)
            atomicAdd(&deg[ei[E + e]], 1);
    } else {
        const int  cb   = gridDim.x - HISTB;
        const long tid0 = (long)(blockIdx.x - HISTB) * blockDim.x + threadIdx.x;
        const long step = (long)cb * blockDim.x;
        const long n8   = (long)E * (EDIM / 8);
        long p = tid0;
        for (; p + 3 * step < n8; p += 4 * step) {
            const long p0 = p, p1 = p + step, p2 = p + 2 * step, p3 = p + 3 * step;
            const float4 a0 = *reinterpret_cast<const float4*>(ea + p0 * 8);
            const float4 b0 = *reinterpret_cast<const float4*>(ea + p0 * 8 + 4);
            const float4 a1 = *reinterpret_cast<const float4*>(ea + p1 * 8);
            const float4 b1 = *reinterpret_cast<const float4*>(ea + p1 * 8 + 4);
            const float4 a2 = *reinterpret_cast<const float4*>(ea + p2 * 8);
            const float4 b2 = *reinterpret_cast<const float4*>(ea + p2 * 8 + 4);
            const float4 a3 = *reinterpret_cast<const float4*>(ea + p3 * 8);
            const float4 b3 = *reinterpret_cast<const float4*>(ea + p3 * 8 + 4);
            *reinterpret_cast<short8v*>(eab + p0 * 8) = pack_bf(a0, b0);
            *reinterpret_cast<short8v*>(eab + p1 * 8) = pack_bf(a1, b1);
            *reinterpret_cast<short8v*>(eab + p2 * 8) = pack_bf(a2, b2);
            *reinterpret_cast<short8v*>(eab + p3 * 8) = pack_bf(a3, b3);
        }
        for (; p < n8; p += step) {
            const float4 a = *reinterpret_cast<const float4*>(ea + p * 8);
            const float4 b = *reinterpret_cast<const float4*>(ea + p * 8 + 4);
            *reinterpret_cast<short8v*>(eab + p * 8) = pack_bf(a, b);
        }
    }
}

// ---------------------------------------------------------------------------
// CSR build step 2: exclusive scan of deg -> rowptr + cursor (8 elems/thread).
// ---------------------------------------------------------------------------
__global__ __launch_bounds__(1024) void scan_build(
    int* __restrict__ cursor, int* __restrict__ rowptr, int N)
{
    __shared__ int wsums[16];
    __shared__ int run_s;
    const int tid  = threadIdx.x;
    const int lane = tid & 63;
    const int w    = tid >> 6;
    if (tid == 0) run_s = 0;
    __syncthreads();
    for (int base = 0; base < N; base += 8192) {
        const int i0 = base + tid * 8;
        int v[8];
#pragma unroll
        for (int k = 0; k < 8; ++k) v[k] = 0;
        if (i0 + 7 < N) {
            const int4 a = *reinterpret_cast<const int4*>(cursor + i0);
            const int4 b = *reinterpret_cast<const int4*>(cursor + i0 + 4);
            v[0] = a.x; v[1] = a.y; v[2] = a.z; v[3] = a.w;
            v[4] = b.x; v[5] = b.y; v[6] = b.z; v[7] = b.w;
        } else if (i0 < N) {
            for (int k = 0; k < 8 && i0 + k < N; ++k) v[k] = cursor[i0 + k];
        }
        const int tsum = ((v[0] + v[1]) + (v[2] + v[3])) + ((v[4] + v[5]) + (v[6] + v[7]));
        int incl = tsum;
#pragma unroll
        for (int off = 1; off < 64; off <<= 1) {
            int t = __shfl_up(incl, off, 64);
            if (lane >= off) incl += t;
        }
        if (lane == 63) wsums[w] = incl;
        __syncthreads();
        if (w == 0) {
            int s = (lane < 16) ? wsums[lane] : 0;
#pragma unroll
            for (int off = 1; off < 16; off <<= 1) {
                int t = __shfl_up(s, off, 64);
                if (lane >= off) s += t;
            }
            if (lane < 16) wsums[lane] = s;
        }
        __syncthreads();
        const int waveoff = (w > 0) ? wsums[w - 1] : 0;
        int acc = run_s + waveoff + incl - tsum;
        if (i0 + 7 < N) {
            int4 ra, rb;
            ra.x = acc;            ra.y = acc + v[0];
            ra.z = ra.y + v[1];    ra.w = ra.z + v[2];
            rb.x = ra.w + v[3];    rb.y = rb.x + v[4];
            rb.z = rb.y + v[5];    rb.w = rb.z + v[6];
            *reinterpret_cast<int4*>(rowptr + i0) = ra;
            *reinterpret_cast<int4*>(rowptr + i0 + 4) = rb;
            *reinterpret_cast<int4*>(cursor + i0) = ra;
            *reinterpret_cast<int4*>(cursor + i0 + 4) = rb;
        } else if (i0 < N) {
            for (int k = 0; k < 8 && i0 + k < N; ++k) {
                rowptr[i0 + k] = acc; cursor[i0 + k] = acc; acc += v[k];
            }
        }
        __syncthreads();
        if (tid == 0) run_s += wsums[15];
        __syncthreads();
    }
    if (tid == 0) rowptr[N] = run_s;
}

// ---------------------------------------------------------------------------
// CSR build step 3: scatter src/dst into slot order + inverse map eidp.
// ---------------------------------------------------------------------------
__global__ __launch_bounds__(256) void scatter_k(
    const int* __restrict__ ei, int* __restrict__ cursor,
    int* __restrict__ srcp, int* __restrict__ dstp,
    int* __restrict__ eidp, int E)
{
    const int e = blockIdx.x * blockDim.x + threadIdx.x;
    if (e < E) {
        const int d = ei[E + e];
        const int p = atomicAdd(&cursor[d], 1);
        srcp[p] = ei[e];
        dstp[p] = d;
        eidp[p] = e;
    }
}

// ---------------------------------------------------------------------------
// Weight prep (merged): We1/We2 -> [128][64] bf16T; W1..W4 -> [128][128] bf16T.
// ---------------------------------------------------------------------------
__global__ __launch_bounds__(128) void prep_all(
    const float* __restrict__ We1, const float* __restrict__ We2,
    const float* __restrict__ W1, const float* __restrict__ W2,
    const float* __restrict__ W3, const float* __restrict__ W4,
    unsigned short* __restrict__ WeT1, unsigned short* __restrict__ WeT2,
    unsigned short* __restrict__ W1T, unsigned short* __restrict__ W2T,
    unsigned short* __restrict__ W3T, unsigned short* __restrict__ W4T)
{
    const int c = blockIdx.x;    // 0..127 output column
    const int k = threadIdx.x;   // 0..127
    if (k < EDIM) {
        WeT1[c * EDIM + k] = f2bf(We1[k * NDIM + c]);
        WeT2[c * EDIM + k] = f2bf(We2[k * NDIM + c]);
    }
    W1T[c * NDIM + k] = f2bf(W1[k * NDIM + c]);
    W2T[c * NDIM + k] = f2bf(W2[k * NDIM + c]);
    W3T[c * NDIM + k] = f2bf(W3[k * NDIM + c]);
    W4T[c * NDIM + k] = f2bf(W4[k * NDIM + c]);
}

// ---------------------------------------------------------------------------
// Edge pass: MFMA + software-pipelined segmented accumulate (r12 form).
// ---------------------------------------------------------------------------
template <bool PERM>
__global__ __launch_bounds__(256) void edge_mfma(
    const float* __restrict__ xnode,
    const float* __restrict__ ea,
    const unsigned short* __restrict__ eab,
    const int*   __restrict__ srcp,
    const int*   __restrict__ eidp,
    const int*   __restrict__ dstp,
    const unsigned short* __restrict__ WeT,
    const float* __restrict__ be,
    float*       __restrict__ aggr,
    int E)
{
    __shared__ float msg[WPB][16][LPAD];

    const int tid   = threadIdx.x;
    const int lane  = tid & 63;
    const int wv    = tid >> 6;
    const int span0 = (blockIdx.x * WPB + wv) * SPAN;
    if (span0 >= E) return;

    const int m16 = lane & 15;
    const int kg  = lane >> 4;
    const int k0a = kg * 8;

    short8v bfrag[2][8];
#pragma unroll
    for (int kk = 0; kk < 2; ++kk)
#pragma unroll
        for (int nt = 0; nt < 8; ++nt) {
            const int col = nt * 16 + m16;
            bfrag[kk][nt] = *reinterpret_cast<const short8v*>(&WeT[col * EDIM + kk * 32 + k0a]);
        }

    const int c0 = lane, c1 = lane + 64;
    const float be0 = be[c0], be1 = be[c1];
    float* msgw = &msg[wv][0][0];

    float a0 = 0.f, a1 = 0.f;

    if (span0 + SPAN <= E) {
        int   sr_c[16], ds_c[16];
        float xv0_c[16], xv1_c[16];
        short8v af_n[2];
        short8v af_nn[2];
        float4 eaf_n[4];
        float4 eaf_nn[4];

        int eid1 = 0, eid2 = 0, eid3 = 0;
        if (PERM) {
            eid1 = eidp[span0 + 16 + m16];
            eid2 = eidp[span0 + 32 + m16];
            eid3 = eidp[span0 + 48 + m16];
        }

#pragma unroll
        for (int s = 0; s < 16; ++s) { sr_c[s] = srcp[span0 + s]; ds_c[s] = dstp[span0 + s]; }
#pragma unroll
        for (int s = 0; s < 16; ++s) {
            xv0_c[s] = xnode[(long)sr_c[s] * NDIM + c0];
            xv1_c[s] = xnode[(long)sr_c[s] * NDIM + c1];
        }
        {
            short8v af0, af1;
            if (PERM) {
                const unsigned short* arow = eab + (size_t)eidp[span0 + m16] * EDIM;
                af0 = *reinterpret_cast<const short8v*>(arow + k0a);
                af1 = *reinterpret_cast<const short8v*>(arow + 32 + k0a);
            } else {
                const float* arow = ea + (long)eidp[span0 + m16] * EDIM;
                af0 = cvt_row(arow, k0a);
                af1 = cvt_row(arow, 32 + k0a);
            }
#pragma unroll
            for (int nt = 0; nt < 8; ++nt) {
                float4v acc = (float4v){0.f, 0.f, 0.f, 0.f};
                acc = __builtin_amdgcn_mfma_f32_16x16x32_bf16(af0, bfrag[0][nt], acc, 0, 0, 0);
                acc = __builtin_amdgcn_mfma_f32_16x16x32_bf16(af1, bfrag[1][nt], acc, 0, 0, 0);
#pragma unroll
                for (int r = 0; r < 4; ++r)
                    msgw[(kg * 4 + r) * LPAD + nt * 16 + m16] = acc[r];
            }
        }
        if (PERM) {
            const unsigned short* arow = eab + (size_t)eid1 * EDIM;
            af_n[0] = *reinterpret_cast<const short8v*>(arow + k0a);
            af_n[1] = *reinterpret_cast<const short8v*>(arow + 32 + k0a);
        } else {
            const float* arow = ea + (long)eidp[span0 + 16 + m16] * EDIM;
            eaf_n[0] = *reinterpret_cast<const float4*>(arow + k0a);
            eaf_n[1] = *reinterpret_cast<const float4*>(arow + k0a + 4);
            eaf_n[2] = *reinterpret_cast<const float4*>(arow + 32 + k0a);
            eaf_n[3] = *reinterpret_cast<const float4*>(arow + 32 + k0a + 4);
        }

        int dcur = ds_c[0];

#pragma unroll
        for (int t = 0; t < SPAN / 16; ++t) {
            const int base = span0 + t * 16;
            const bool hn  = (t + 1 < SPAN / 16);
            const bool hnn = (t + 2 < SPAN / 16);
            int   sr_n[16], ds_n[16];
            float xv0_n[16], xv1_n[16];

            if (hn) {
#pragma unroll
                for (int s = 0; s < 16; ++s) {
                    sr_n[s] = srcp[base + 16 + s];
                    ds_n[s] = dstp[base + 16 + s];
                }
#pragma unroll
                for (int s = 0; s < 16; ++s) {
                    xv0_n[s] = xnode[(long)sr_n[s] * NDIM + c0];
                    xv1_n[s] = xnode[(long)sr_n[s] * NDIM + c1];
                }
            }

            if (hnn) {
                if (PERM) {
                    const int eidx = (t == 0) ? eid2 : eid3;
                    const unsigned short* arow = eab + (size_t)eidx * EDIM;
                    af_nn[0] = *reinterpret_cast<const short8v*>(arow + k0a);
                    af_nn[1] = *reinterpret_cast<const short8v*>(arow + 32 + k0a);
                } else {
                    const float* arow = ea + (long)eidp[base + 32 + m16] * EDIM;
                    eaf_nn[0] = *reinterpret_cast<const float4*>(arow + k0a);
                    eaf_nn[1] = *reinterpret_cast<const float4*>(arow + k0a + 4);
                    eaf_nn[2] = *reinterpret_cast<const float4*>(arow + 32 + k0a);
                    eaf_nn[3] = *reinterpret_cast<const float4*>(arow + 32 + k0a + 4);
                }
            }

#pragma unroll
            for (int s = 0; s < 16; ++s) {
                if (ds_c[s] != dcur) {
                    atomicAdd(&aggr[(long)dcur * NDIM + c0], a0);
                    atomicAdd(&aggr[(long)dcur * NDIM + c1], a1);
                    a0 = 0.f; a1 = 0.f; dcur = ds_c[s];
                }
                a0 += fmaxf(xv0_c[s] + msgw[s * LPAD + c0] + be0, 0.f);
                a1 += fmaxf(xv1_c[s] + msgw[s * LPAD + c1] + be1, 0.f);
            }

            if (hn) {
                short8v af0, af1;
                if (PERM) { af0 = af_n[0]; af1 = af_n[1]; }
                else      { af0 = pack_bf(eaf_n[0], eaf_n[1]); af1 = pack_bf(eaf_n[2], eaf_n[3]); }
#pragma unroll
                for (int nt = 0; nt < 8; ++nt) {
                    float4v acc = (float4v){0.f, 0.f, 0.f, 0.f};
                    acc = __builtin_amdgcn_mfma_f32_16x16x32_bf16(af0, bfrag[0][nt], acc, 0, 0, 0);
                    acc = __builtin_amdgcn_mfma_f32_16x16x32_bf16(af1, bfrag[1][nt], acc, 0, 0, 0);
#pragma unroll
                    for (int r = 0; r < 4; ++r)
                        msgw[(kg * 4 + r) * LPAD + nt * 16 + m16] = acc[r];
                }
                if (PERM) {
                    af_n[0] = af_nn[0]; af_n[1] = af_nn[1];
                } else {
#pragma unroll
                    for (int i = 0; i < 4; ++i) eaf_n[i] = eaf_nn[i];
                }
#pragma unroll
                for (int s = 0; s < 16; ++s) {
                    sr_c[s] = sr_n[s]; ds_c[s] = ds_n[s];
                    xv0_c[s] = xv0_n[s]; xv1_c[s] = xv1_n[s];
                }
            }
        }
        atomicAdd(&aggr[(long)dcur * NDIM + c0], a0);
        atomicAdd(&aggr[(long)dcur * NDIM + c1], a1);
    } else {
        const int spanEnd = E;
        int dcur = dstp[span0];
        for (int t = 0; t < SPAN / 16; ++t) {
            const int base = span0 + t * 16;
            if (base >= spanEnd) break;

            const int slot = (base + m16 < E) ? base + m16 : E - 1;
            short8v afrag[2];
            if (PERM) {
                const unsigned short* arow = eab + (size_t)eidp[slot] * EDIM;
                afrag[0] = *reinterpret_cast<const short8v*>(arow + k0a);
                afrag[1] = *reinterpret_cast<const short8v*>(arow + 32 + k0a);
            } else {
                const float* arow = ea + (long)eidp[slot] * EDIM;
                afrag[0] = cvt_row(arow, k0a);
                afrag[1] = cvt_row(arow, 32 + k0a);
            }

#pragma unroll
            for (int nt = 0; nt < 8; ++nt) {
                float4v acc = (float4v){0.f, 0.f, 0.f, 0.f};
                acc = __builtin_amdgcn_mfma_f32_16x16x32_bf16(afrag[0], bfrag[0][nt], acc, 0, 0, 0);
                acc = __builtin_amdgcn_mfma_f32_16x16x32_bf16(afrag[1], bfrag[1][nt], acc, 0, 0, 0);
#pragma unroll
                for (int r = 0; r < 4; ++r)
                    msgw[(kg * 4 + r) * LPAD + nt * 16 + m16] = acc[r];
            }

            for (int s = 0; s < 16; ++s) {
                const int gs = base + s;
                if (gs >= spanEnd) break;
                const int d  = dstp[gs];
                const int sr = srcp[gs];
                if (d != dcur) {
                    atomicAdd(&aggr[(long)dcur * NDIM + c0], a0);
                    atomicAdd(&aggr[(long)dcur * NDIM + c1], a1);
                    a0 = 0.f; a1 = 0.f; dcur = d;
                }
                const float xv0 = xnode[(long)sr * NDIM + c0];
                const float xv1 = xnode[(long)sr * NDIM + c1];
                a0 += fmaxf(xv0 + msgw[s * LPAD + c0] + be0, 0.f);
                a1 += fmaxf(xv1 + msgw[s * LPAD + c1] + be1, 0.f);
            }
        }
        atomicAdd(&aggr[(long)dcur * NDIM + c0], a0);
        atomicAdd(&aggr[(long)dcur * NDIM + c1], a1);
    }
}

// ---------------------------------------------------------------------------
// Node MLP via MFMA, weights staged in LDS (r14 form, kept).
// ---------------------------------------------------------------------------
template <bool FINAL_RELU, bool STATS>
__global__ __launch_bounds__(256) void node_mlp_mfma(
    const float* xin,                    // may alias out (same-row read->write)
    const float* __restrict__ aggr,
    const unsigned short* __restrict__ W1T, const float* __restrict__ b1,
    const unsigned short* __restrict__ W2T, const float* __restrict__ b2,
    float* out,
    float* __restrict__ stats,
    int N)
{
    __shared__ unsigned short w1s[NDIM][WPITCH];
    __shared__ unsigned short w2s[NDIM][WPITCH];
    __shared__ unsigned short in_lds[16][PITCH];
    __shared__ unsigned short t_lds[16][PITCH];

    const int tid  = threadIdx.x;
    const int lane = tid & 63;
    const int wv   = tid >> 6;
    const int wn0  = wv * 32;
    const int m16  = lane & 15;
    const int rg   = lane >> 4;

    {
        const int col = tid >> 1;
        const int h   = (tid & 1) * 64;
#pragma unroll
        for (int j = 0; j < 8; ++j) {
            *reinterpret_cast<short8v*>(&w1s[col][h + j * 8]) =
                *reinterpret_cast<const short8v*>(&W1T[col * NDIM + h + j * 8]);
            *reinterpret_cast<short8v*>(&w2s[col][h + j * 8]) =
                *reinterpret_cast<const short8v*>(&W2T[col * NDIM + h + j * 8]);
        }
    }
    float bias1[2], bias2[2];
#pragma unroll
    for (int nt = 0; nt < 2; ++nt) {
        bias1[nt] = b1[wn0 + nt * 16 + m16];
        bias2[nt] = b2[wn0 + nt * 16 + m16];
    }
    __syncthreads();

    float ss[2] = {0.f, 0.f}, sq[2] = {0.f, 0.f};

    const int ntile = (N + 15) >> 4;
    for (int tile = blockIdx.x; tile < ntile; tile += gridDim.x) {
        const int nb = tile << 4;

        {
            const int row = tid >> 4;
            const int ch  = tid & 15;
            const int gr  = nb + row;
            short8v pk = (short8v){0, 0, 0, 0, 0, 0, 0, 0};
            if (gr < N) {
                const float4* xp = reinterpret_cast<const float4*>(xin  + (size_t)gr * NDIM + ch * 8);
                const float4* ap = reinterpret_cast<const float4*>(aggr + (size_t)gr * NDIM + ch * 8);
                const float4 x0 = xp[0], x1 = xp[1];
                const float4 g0 = ap[0], g1 = ap[1];
                pk[0] = (short)f2bf(x0.x + g0.x); pk[1] = (short)f2bf(x0.y + g0.y);
                pk[2] = (short)f2bf(x0.z + g0.z); pk[3] = (short)f2bf(x0.w + g0.w);
                pk[4] = (short)f2bf(x1.x + g1.x); pk[5] = (short)f2bf(x1.y + g1.y);
                pk[6] = (short)f2bf(x1.z + g1.z); pk[7] = (short)f2bf(x1.w + g1.w);
            }
            *reinterpret_cast<short8v*>(&in_lds[row][ch * 8]) = pk;
        }
        __syncthreads();

        short8v af[4];
#pragma unroll
        for (int kt = 0; kt < 4; ++kt)
            af[kt] = *reinterpret_cast<const short8v*>(&in_lds[m16][kt * 32 + rg * 8]);
        float4v acc[2];
#pragma unroll
        for (int nt = 0; nt < 2; ++nt) {
            acc[nt] = (float4v){0.f, 0.f, 0.f, 0.f};
#pragma unroll
            for (int kt = 0; kt < 4; ++kt) {
                const short8v bf = *reinterpret_cast<const short8v*>(
                    &w1s[wn0 + nt * 16 + m16][kt * 32 + rg * 8]);
                acc[nt] = __builtin_amdgcn_mfma_f32_16x16x32_bf16(af[kt], bf, acc[nt], 0, 0, 0);
            }
        }
#pragma unroll
        for (int nt = 0; nt < 2; ++nt)
#pragma unroll
            for (int r = 0; r < 4; ++r) {
                const float v = fmaxf(acc[nt][r] + bias1[nt], 0.f);
                t_lds[rg * 4 + r][wn0 + nt * 16 + m16] = f2bf(v);
            }
        __syncthreads();

#pragma unroll
        for (int kt = 0; kt < 4; ++kt)
            af[kt] = *reinterpret_cast<const short8v*>(&t_lds[m16][kt * 32 + rg * 8]);
        float4v acc2[2];
#pragma unroll
        for (int nt = 0; nt < 2; ++nt) {
            acc2[nt] = (float4v){0.f, 0.f, 0.f, 0.f};
#pragma unroll
            for (int kt = 0; kt < 4; ++kt) {
                const short8v bf = *reinterpret_cast<const short8v*>(
                    &w2s[wn0 + nt * 16 + m16][kt * 32 + rg * 8]);
                acc2[nt] = __builtin_amdgcn_mfma_f32_16x16x32_bf16(af[kt], bf, acc2[nt], 0, 0, 0);
            }
        }

#pragma unroll
        for (int nt = 0; nt < 2; ++nt)
#pragma unroll
            for (int r = 0; r < 4; ++r) {
                const int node = nb + rg * 4 + r;
                if (node < N) {
                    float o = acc2[nt][r] + bias2[nt];
                    if (FINAL_RELU) o = fmaxf(o, 0.f);
                    out[(size_t)node * NDIM + wn0 + nt * 16 + m16] = o;
                    if (STATS) { ss[nt] += o; sq[nt] += o * o; }
                }
            }
    }

    if (STATS) {
#pragma unroll
        for (int nt = 0; nt < 2; ++nt) {
            float s = ss[nt], q = sq[nt];
            s += __shfl_xor(s, 16); q += __shfl_xor(q, 16);
            s += __shfl_xor(s, 32); q += __shfl_xor(q, 32);
            if (rg == 0) {
                atomicAdd(&stats[wn0 + nt * 16 + m16], s);
                atomicAdd(&stats[NDIM + wn0 + nt * 16 + m16], q);
            }
        }
    }
}

// ---------------------------------------------------------------------------
// BatchNorm apply (in place), 4x strided unroll.
// ---------------------------------------------------------------------------
__global__ __launch_bounds__(256) void bn_apply(
    float* out,
    const float* __restrict__ stats,
    const float* __restrict__ gamma,
    const float* __restrict__ beta,
    int N)
{
    __shared__ float sc_s[NDIM];
    __shared__ float sh_s[NDIM];
    const float invN = 1.f / (float)N;
    if (threadIdx.x < NDIM) {
        const int f = threadIdx.x;
        const float mean = stats[f] * invN;
        const float var  = stats[NDIM + f] * invN - mean * mean;
        const float sc   = gamma[f] * rsqrtf(var + BN_EPS);
        sc_s[f] = sc;
        sh_s[f] = beta[f] - mean * sc;
    }
    __syncthreads();

    const int total4 = N * (NDIM / 4);
    const int step   = gridDim.x * blockDim.x;
    float4* o4 = reinterpret_cast<float4*>(out);
    int idx = blockIdx.x * blockDim.x + threadIdx.x;
    for (; idx + 3 * step < total4; idx += 4 * step) {
        const int i0 = idx, i1 = idx + step, i2 = idx + 2 * step, i3 = idx + 3 * step;
        float4 p0 = o4[i0], p1 = o4[i1], p2 = o4[i2], p3 = o4[i3];
        const int f0 = (i0 & 31) * 4, f1 = (i1 & 31) * 4, f2 = (i2 & 31) * 4, f3 = (i3 & 31) * 4;
        p0.x = p0.x * sc_s[f0 + 0] + sh_s[f0 + 0]; p0.y = p0.y * sc_s[f0 + 1] + sh_s[f0 + 1];
        p0.z = p0.z * sc_s[f0 + 2] + sh_s[f0 + 2]; p0.w = p0.w * sc_s[f0 + 3] + sh_s[f0 + 3];
        p1.x = p1.x * sc_s[f1 + 0] + sh_s[f1 + 0]; p1.y = p1.y * sc_s[f1 + 1] + sh_s[f1 + 1];
        p1.z = p1.z * sc_s[f1 + 2] + sh_s[f1 + 2]; p1.w = p1.w * sc_s[f1 + 3] + sh_s[f1 + 3];
        p2.x = p2.x * sc_s[f2 + 0] + sh_s[f2 + 0]; p2.y = p2.y * sc_s[f2 + 1] + sh_s[f2 + 1];
        p2.z = p2.z * sc_s[f2 + 2] + sh_s[f2 + 2]; p2.w = p2.w * sc_s[f2 + 3] + sh_s[f2 + 3];
        p3.x = p3.x * sc_s[f3 + 0] + sh_s[f3 + 0]; p3.y = p3.y * sc_s[f3 + 1] + sh_s[f3 + 1];
        p3.z = p3.z * sc_s[f3 + 2] + sh_s[f3 + 2]; p3.w = p3.w * sc_s[f3 + 3] + sh_s[f3 + 3];
        o4[i0] = p0; o4[i1] = p1; o4[i2] = p2; o4[i3] = p3;
    }
    for (; idx < total4; idx += step) {
        const int fb = (idx & 31) * 4;
        float4 p = o4[idx];
        p.x = p.x * sc_s[fb + 0] + sh_s[fb + 0];
        p.y = p.y * sc_s[fb + 1] + sh_s[fb + 1];
        p.z = p.z * sc_s[fb + 2] + sh_s[fb + 2];
        p.w = p.w * sc_s[fb + 3] + sh_s[fb + 3];
        o4[idx] = p;
    }
}

// ---------------------------------------------------------------------------
extern "C" void kernel_launch(void* const* d_in, const int* in_sizes, int n_in,
                              void* d_out, int out_size, void* d_ws, size_t ws_size,
                              hipStream_t stream)
{
    const float* x    = (const float*)d_in[0];
    const int*   ei   = (const int*)  d_in[1];
    const float* ea   = (const float*)d_in[2];
    const float* We1  = (const float*)d_in[3];
    const float* be1  = (const float*)d_in[4];
    const float* W1   = (const float*)d_in[5];
    const float* b1   = (const float*)d_in[6];
    const float* W2   = (const float*)d_in[7];
    const float* b2   = (const float*)d_in[8];
    const float* We2  = (const float*)d_in[9];
    const float* be2  = (const float*)d_in[10];
    const float* W3   = (const float*)d_in[11];
    const float* b3   = (const float*)d_in[12];
    const float* W4   = (const float*)d_in[13];
    const float* b4   = (const float*)d_in[14];
    const float* gamma = (const float*)d_in[15];
    const float* beta  = (const float*)d_in[16];

    const int N = in_sizes[0] / NDIM;
    const int E = in_sizes[1] / 2;

    // workspace layout (aggr first; all 16B-aligned)
    float*          aggr   = (float*)d_ws;                            // [N*128]
    unsigned short* WeT1   = (unsigned short*)(aggr + (size_t)N * NDIM);
    unsigned short* WeT2   = WeT1 + NDIM * EDIM;
    unsigned short* W1T    = WeT2 + NDIM * EDIM;                      // [128*128]
    unsigned short* W2T    = W1T + NDIM * NDIM;
    unsigned short* W3T    = W2T + NDIM * NDIM;
    unsigned short* W4T    = W3T + NDIM * NDIM;
    int*            rowptr = (int*)(W4T + NDIM * NDIM);               // [N+1]
    int*            cursor = rowptr + (N + 1);                        // [N]
    int*            srcp   = cursor + N;                              // [E]
    int*            dstp   = srcp + E;                                // [E]
    int*            eidp   = dstp + E;                                // [E]
    float*          stats  = (float*)(eidp + E);                      // [256]
    unsigned short* eab    = (unsigned short*)(stats + 2 * NDIM);     // [E*64] bf16

    const size_t need_perm = (size_t)((char*)eab - (char*)d_ws) + (size_t)E * EDIM * 2 + 64;
    const bool   perm      = ws_size >= need_perm;

    hipMemsetAsync(cursor, 0, (size_t)N * sizeof(int), stream);
    hipMemsetAsync(stats, 0, 2 * NDIM * sizeof(float), stream);

    // ---- CSR build (hist + cvt concurrent by block) + weight prep ----
    hist_cvt_k<<<2048, 256, 0, stream>>>(ei, cursor, ea, eab, E, perm ? 1 : 0);
    scan_build<<<1, 1024, 0, stream>>>(cursor, rowptr, N);
    scatter_k<<<(E + 255) / 256, 256, 0, stream>>>(ei, cursor, srcp, dstp, eidp, E);
    prep_all<<<NDIM, NDIM, 0, stream>>>(We1, We2, W1, W2, W3, W4,
                                        WeT1, WeT2, W1T, W2T, W3T, W4T);

    const int egrid = (E + WPB * SPAN - 1) / (WPB * SPAN);
    const int mgrid = 512;   // 2 blocks/CU (78KB LDS), ~6 tiles each
    float* h = (float*)d_out;

    // ---- conv1 ----
    hipMemsetAsync(aggr, 0, (size_t)N * NDIM * sizeof(float), stream);
    if (perm)
        edge_mfma<true><<<egrid, 256, 0, stream>>>(x, ea, eab, srcp, eidp, dstp, WeT1, be1, aggr, E);
    else
        edge_mfma<false><<<egrid, 256, 0, stream>>>(x, ea, eab, srcp, eidp, dstp, WeT1, be1, aggr, E);
    node_mlp_mfma<true, false><<<mgrid, 256, 0, stream>>>(x, aggr, W1T, b1, W2T, b2,
                                                          h, nullptr, N);
    // ---- conv2 ----
    hipMemsetAsync(aggr, 0, (size_t)N * NDIM * sizeof(float), stream);
    if (perm)
        edge_mfma<true><<<egrid, 256, 0, stream>>>(h, ea, eab, srcp, eidp, dstp, WeT2, be2, aggr, E);
    else
        edge_mfma<false><<<egrid, 256, 0, stream>>>(h, ea, eab, srcp, eidp, dstp, WeT2, be2, aggr, E);
    node_mlp_mfma<false, true><<<mgrid, 256, 0, stream>>>(h, aggr, W3T, b3, W4T, b4,
                                                          h, stats, N);
    // ---- batch norm ----
    bn_apply<<<1024, 256, 0, stream>>>(h, stats, gamma, beta, N);
}